// Round 7
// baseline (68606.268 us; speedup 1.0000x reference)
//
#include <hip/hip_runtime.h>
#include <stdint.h>

// TinyGRU R7 (= R6 + compile fix): split MFMA kernels (CPB=4, 128 blocks).
//  1. x / h1 A-fragments loaded DIRECTLY from global into registers (lane's
//     fragment = contiguous 16/32B chunk; chain col>>2 replicated x4) -> LDS
//     reads drop 8->4 (rec1) and 6->4 (rec0) per wave per step.
//  2. Conflict-free h LDS layout (chains at rows c*HC, HC=140, reads 4-lane
//     broadcast at arow=col>>2): <=2-way bank aliasing (free).
//  3. Non-draining per-step barrier: s_waitcnt(lgkmcnt(0) only) + raw
//     s_barrier, so the depth-2 global prefetch queue (t+2) stays in flight
//     across barriers (~1400cyc cover > 900cyc HBM latency). Plain
//     __syncthreads would insert vmcnt(0) and serialize the prefetch.

typedef _Float16 half_t;
typedef _Float16 half8 __attribute__((ext_vector_type(8)));
typedef __fp16  fp16x2 __attribute__((ext_vector_type(2)));
typedef float f32x4 __attribute__((ext_vector_type(4)));

#define SS 1024
#define CPB 4
#define NBLK 128
#define HC 140            // LDS row stride for 128-wide h (f16 elems)

#define MFMA16(a, b, c) __builtin_amdgcn_mfma_f32_16x16x32_f16(a, b, c, 0, 0, 0)

// lgkmcnt(0), vmcnt=63 (no wait), expcnt=7 (no wait)  [gfx9 encoding]
#define BAR() do { __builtin_amdgcn_sched_barrier(0);                 \
                   __builtin_amdgcn_s_waitcnt(0xC07F);                \
                   __builtin_amdgcn_s_barrier();                      \
                   __builtin_amdgcn_sched_barrier(0); } while (0)

__device__ __forceinline__ float sigmoidf_(float x) {
    return __builtin_amdgcn_rcpf(1.0f + __expf(-x));
}
__device__ __forceinline__ float tanhf_(float x) {
    return 1.0f - 2.0f * __builtin_amdgcn_rcpf(1.0f + __expf(2.0f * x));
}
union H8 { half8 v; fp16x2 p[4]; };
__device__ __forceinline__ half8 pack8(f32x4 a, f32x4 b) {
    H8 u;
    u.p[0] = __builtin_amdgcn_cvt_pkrtz(a[0], a[1]);
    u.p[1] = __builtin_amdgcn_cvt_pkrtz(a[2], a[3]);
    u.p[2] = __builtin_amdgcn_cvt_pkrtz(b[0], b[1]);
    u.p[3] = __builtin_amdgcn_cvt_pkrtz(b[2], b[3]);
    return u.v;
}
__device__ __forceinline__ half8 cvt8(const float* p) {
    return pack8(*(const f32x4*)p, *(const f32x4*)(p + 4));
}

// ---------------- Layer 0: x[B,S,64] f32 -> h1[B,S,128] f16 ----------------
__global__ __launch_bounds__(512, 2)
void gru_rec0(const float* __restrict__ x, const float* __restrict__ Wih,
              const float* __restrict__ Whh, const float* __restrict__ bih,
              const float* __restrict__ bhh, half_t* __restrict__ h1)
{
    const int tid  = threadIdx.x;
    const int w    = tid >> 6;
    const int lane = tid & 63;
    const int quad = lane >> 4;
    const int col  = lane & 15;
    const int cb   = blockIdx.x * CPB;

    __shared__ alignas(16) half_t s_h[2][CPB * HC];

    const int rr = w * 16 + col;
    half8 Bxr[2], Bxz[2], Bxn[2];       // Wih (K=64)
    half8 Bhr[4], Bhz[4], Bhn[4];       // Whh (K=128)
#pragma unroll
    for (int s = 0; s < 2; ++s) {
        Bxr[s] = cvt8(Wih + (rr      ) * 64 + s * 32 + quad * 8);
        Bxz[s] = cvt8(Wih + (rr + 128) * 64 + s * 32 + quad * 8);
        Bxn[s] = cvt8(Wih + (rr + 256) * 64 + s * 32 + quad * 8);
    }
#pragma unroll
    for (int s = 0; s < 4; ++s) {
        Bhr[s] = cvt8(Whh + (rr      ) * 128 + s * 32 + quad * 8);
        Bhz[s] = cvt8(Whh + (rr + 128) * 128 + s * 32 + quad * 8);
        Bhn[s] = cvt8(Whh + (rr + 256) * 128 + s * 32 + quad * 8);
    }
    const float br  = bih[rr] + bhh[rr];
    const float bz  = bih[128 + rr] + bhh[128 + rr];
    const float bni = bih[256 + rr];
    const float bnh = bhh[256 + rr];

    for (int i = tid; i < CPB * HC; i += 512) s_h[0][i] = (half_t)0.0f;

    // A-fragment global source: chain = col>>2 (4-lane replicated)
    const float* xA = x + ((size_t)(cb + (col >> 2)) * SS) * 64 + quad * 8;
    f32x4 xq[2][2][2];                  // [t-parity][s][lo/hi]
#pragma unroll
    for (int sl = 0; sl < 2; ++sl)
#pragma unroll
        for (int s = 0; s < 2; ++s) {
            xq[sl][s][0] = *(const f32x4*)(xA + sl * 64 + s * 32);
            xq[sl][s][1] = *(const f32x4*)(xA + sl * 64 + s * 32 + 4);
        }

    // h1 copy-out mapping (256 threads, 4B each)
    const int c  = (tid >> 6) & 3;
    const int sc = tid & 63;
    uint32_t* h1u = (uint32_t*)(h1 + (size_t)(cb + c) * SS * 128) + sc;

    __syncthreads();

    float hp = 0.0f;
    const int aoff = (col >> 2) * HC + quad * 8;

    for (int t = 0; t < SS; ++t) {
        const int cur = t & 1, nxt = cur ^ 1;

        // global store of h[t-1] (stable in s_h[cur])
        if (t >= 1 && tid < 256) {
            uint32_t v = *(const uint32_t*)&s_h[cur][c * HC + 2 * sc];
            h1u[(size_t)(t - 1) * 64] = v;
        }

        // convert this step's x fragments, then refill queue slot for t+2
        half8 ax[2];
#pragma unroll
        for (int s = 0; s < 2; ++s) ax[s] = pack8(xq[cur][s][0], xq[cur][s][1]);
        if (t + 2 < SS) {
            const float* p = xA + (size_t)(t + 2) * 64;
#pragma unroll
            for (int s = 0; s < 2; ++s) {
                xq[cur][s][0] = *(const f32x4*)(p + s * 32);
                xq[cur][s][1] = *(const f32x4*)(p + s * 32 + 4);
            }
        }

        f32x4 ar  = {br, br, br, br},     az  = {bz, bz, bz, bz};
        f32x4 ani = {bni, bni, bni, bni}, anh = {bnh, bnh, bnh, bnh};
#pragma unroll
        for (int s = 0; s < 2; ++s) {
            ar  = MFMA16(ax[s], Bxr[s], ar);
            az  = MFMA16(ax[s], Bxz[s], az);
            ani = MFMA16(ax[s], Bxn[s], ani);
        }
#pragma unroll
        for (int s = 0; s < 4; ++s) {
            half8 ah = *(const half8*)&s_h[cur][aoff + s * 32];
            ar  = MFMA16(ah, Bhr[s], ar);
            az  = MFMA16(ah, Bhz[s], az);
            anh = MFMA16(ah, Bhn[s], anh);
        }
        {   // chain = quad (D row 4*quad, reg 0); write h row = quad
            float r = sigmoidf_(ar[0]);
            float z = sigmoidf_(az[0]);
            float n = tanhf_(ani[0] + r * anh[0]);
            hp = n + z * (hp - n);
            s_h[nxt][quad * HC + rr] = (half_t)hp;
        }
        BAR();
    }
    if (tid < 256) {    // final h[1023] sits in s_h[0]
        uint32_t v = *(const uint32_t*)&s_h[0][c * HC + 2 * sc];
        h1u[(size_t)(SS - 1) * 64] = v;
    }
}

// ------------- Layer 1: h1[B,S,128] f16 -> FC -> out[B,10] f32 -------------
__global__ __launch_bounds__(512, 2)
void gru_rec1(const half_t* __restrict__ h1, const float* __restrict__ Wih,
              const float* __restrict__ Whh, const float* __restrict__ bih,
              const float* __restrict__ bhh, const float* __restrict__ fcw,
              const float* __restrict__ fcb, float* __restrict__ out)
{
    const int tid  = threadIdx.x;
    const int w    = tid >> 6;
    const int lane = tid & 63;
    const int quad = lane >> 4;
    const int col  = lane & 15;
    const int cb   = blockIdx.x * CPB;

    __shared__ alignas(16) half_t s_h[2][CPB * HC];

    const int rr = w * 16 + col;
    half8 Bxr[4], Bxz[4], Bxn[4];       // Wih (K=128)
    half8 Bhr[4], Bhz[4], Bhn[4];       // Whh (K=128)
#pragma unroll
    for (int s = 0; s < 4; ++s) {
        Bxr[s] = cvt8(Wih + (rr      ) * 128 + s * 32 + quad * 8);
        Bxz[s] = cvt8(Wih + (rr + 128) * 128 + s * 32 + quad * 8);
        Bxn[s] = cvt8(Wih + (rr + 256) * 128 + s * 32 + quad * 8);
        Bhr[s] = cvt8(Whh + (rr      ) * 128 + s * 32 + quad * 8);
        Bhz[s] = cvt8(Whh + (rr + 128) * 128 + s * 32 + quad * 8);
        Bhn[s] = cvt8(Whh + (rr + 256) * 128 + s * 32 + quad * 8);
    }
    const float br  = bih[rr] + bhh[rr];
    const float bz  = bih[128 + rr] + bhh[128 + rr];
    const float bni = bih[256 + rr];
    const float bnh = bhh[256 + rr];

    for (int i = tid; i < CPB * HC; i += 512) s_h[0][i] = (half_t)0.0f;

    // x (= h0 stream) A-fragments straight from global, depth-2 queue
    const half_t* xA = h1 + ((size_t)(cb + (col >> 2)) * SS) * 128 + quad * 8;
    half8 hq[2][4];
#pragma unroll
    for (int sl = 0; sl < 2; ++sl)
#pragma unroll
        for (int s = 0; s < 4; ++s)
            hq[sl][s] = *(const half8*)(xA + sl * 128 + s * 32);

    __syncthreads();

    float hp = 0.0f;
    const int aoff = (col >> 2) * HC + quad * 8;

    for (int t = 0; t < SS; ++t) {
        const int cur = t & 1, nxt = cur ^ 1;

        f32x4 ar  = {br, br, br, br},     az  = {bz, bz, bz, bz};
        f32x4 ani = {bni, bni, bni, bni}, anh = {bnh, bnh, bnh, bnh};
#pragma unroll
        for (int s = 0; s < 4; ++s) {
            half8 ax = hq[cur][s];
            half8 ah = *(const half8*)&s_h[cur][aoff + s * 32];
            ar  = MFMA16(ax, Bxr[s], ar);
            ar  = MFMA16(ah, Bhr[s], ar);
            az  = MFMA16(ax, Bxz[s], az);
            az  = MFMA16(ah, Bhz[s], az);
            ani = MFMA16(ax, Bxn[s], ani);
            anh = MFMA16(ah, Bhn[s], anh);
        }
        // refill queue slot for t+2 (WAR on hq[cur] keeps order after MFMAs)
        if (t + 2 < SS) {
            const half_t* p = xA + (size_t)(t + 2) * 128;
#pragma unroll
            for (int s = 0; s < 4; ++s) hq[cur][s] = *(const half8*)(p + s * 32);
        }
        {
            float r = sigmoidf_(ar[0]);
            float z = sigmoidf_(az[0]);
            float n = tanhf_(ani[0] + r * anh[0]);
            hp = n + z * (hp - n);
            s_h[nxt][quad * HC + rr] = (half_t)hp;
        }
        BAR();
    }
    __syncthreads();

    // FC epilogue: h_final (t=1023 wrote buffer 0) rows 0..3
    if (tid < 40) {
        const int ch = tid / 10, cl = tid - ch * 10;
        float acc = fcb[cl];
        const float* wr = fcw + cl * 128;
        const half_t* hv = &s_h[0][ch * HC];
#pragma unroll 8
        for (int k = 0; k < 128; ++k) acc += (float)hv[k] * wr[k];
        out[(cb + ch) * 10 + cl] = acc;
    }
}

extern "C" void kernel_launch(void* const* d_in, const int* in_sizes, int n_in,
                              void* d_out, int out_size, void* d_ws, size_t ws_size,
                              hipStream_t stream) {
    const float* x    = (const float*)d_in[0];
    const float* Wih0 = (const float*)d_in[1];
    const float* Whh0 = (const float*)d_in[2];
    const float* bih0 = (const float*)d_in[3];
    const float* bhh0 = (const float*)d_in[4];
    const float* Wih1 = (const float*)d_in[5];
    const float* Whh1 = (const float*)d_in[6];
    const float* bih1 = (const float*)d_in[7];
    const float* bhh1 = (const float*)d_in[8];
    const float* fcw  = (const float*)d_in[9];
    const float* fcb  = (const float*)d_in[10];

    half_t* h1 = (half_t*)d_ws;   // [512,1024,128] f16 = 134 MB

    gru_rec0<<<NBLK, 512, 0, stream>>>(x, Wih0, Whh0, bih0, bhh0, h1);
    gru_rec1<<<NBLK, 512, 0, stream>>>(h1, Wih1, Whh1, bih1, bhh1, fcw, fcb,
                                       (float*)d_out);
}

// Round 8
// 1320.735 us; speedup vs baseline: 51.9455x; 51.9455x over previous
//
#include <hip/hip_runtime.h>
#include <stdint.h>

// TinyGRU R8 = R6 structure with the scratch bug fixed: the timestep loop is
// unrolled x2 so ALL fragment queues / LDS buffer parities are indexed by
// compile-time constants (R7's hq[cur] with runtime cur was demoted to
// scratch -> 68ms). Features:
//  1. x / h1 A-fragments loaded DIRECTLY from global into registers (lane's
//     fragment = contiguous chunk; chain col>>2 replicated x4): fewer LDS
//     reads per step.
//  2. Conflict-free h LDS layout (chain rows at c*HC, HC=140; reads 4-lane
//     broadcast): <=2-way bank aliasing (free).
//  3. Non-draining per-step barrier: s_waitcnt(lgkmcnt(0) only) + raw
//     s_barrier keeps the depth-2 global prefetch in flight across steps.

typedef _Float16 half_t;
typedef _Float16 half8 __attribute__((ext_vector_type(8)));
typedef __fp16  fp16x2 __attribute__((ext_vector_type(2)));
typedef float f32x4 __attribute__((ext_vector_type(4)));

#define SS 1024
#define CPB 4
#define NBLK 128
#define HC 140            // LDS row stride for 128-wide h (f16 elems)

#define MFMA16(a, b, c) __builtin_amdgcn_mfma_f32_16x16x32_f16(a, b, c, 0, 0, 0)

// lgkmcnt(0), vmcnt=63 (no wait), expcnt=7 (no wait)  [gfx9 encoding]
#define BAR() do { __builtin_amdgcn_sched_barrier(0);                 \
                   __builtin_amdgcn_s_waitcnt(0xC07F);                \
                   __builtin_amdgcn_s_barrier();                      \
                   __builtin_amdgcn_sched_barrier(0); } while (0)

__device__ __forceinline__ float sigmoidf_(float x) {
    return __builtin_amdgcn_rcpf(1.0f + __expf(-x));
}
__device__ __forceinline__ float tanhf_(float x) {
    return 1.0f - 2.0f * __builtin_amdgcn_rcpf(1.0f + __expf(2.0f * x));
}
union H8 { half8 v; fp16x2 p[4]; };
__device__ __forceinline__ half8 pack8(f32x4 a, f32x4 b) {
    H8 u;
    u.p[0] = __builtin_amdgcn_cvt_pkrtz(a[0], a[1]);
    u.p[1] = __builtin_amdgcn_cvt_pkrtz(a[2], a[3]);
    u.p[2] = __builtin_amdgcn_cvt_pkrtz(b[0], b[1]);
    u.p[3] = __builtin_amdgcn_cvt_pkrtz(b[2], b[3]);
    return u.v;
}
__device__ __forceinline__ half8 cvt8(const float* p) {
    return pack8(*(const f32x4*)p, *(const f32x4*)(p + 4));
}

// ---------------- Layer 0: x[B,S,64] f32 -> h1[B,S,128] f16 ----------------
// Step body, P = buffer parity (compile-time). xqX = this parity's x queue
// (4 x f32x4: s0.lo, s0.hi, s1.lo, s1.hi), refilled for t+2 after use.
#define R0_STEP(P, xqX, t)                                                  \
    {                                                                       \
        if ((t) >= 1 && tid < 256) {                                        \
            uint32_t v = *(const uint32_t*)&s_h[P][c * HC + 2 * sc];        \
            h1u[(size_t)((t) - 1) * 64] = v;                                \
        }                                                                   \
        half8 ax0 = pack8(xqX[0], xqX[1]);                                  \
        half8 ax1 = pack8(xqX[2], xqX[3]);                                  \
        if ((t) + 2 < SS) {                                                 \
            const float* p = xA + (size_t)((t) + 2) * 64;                   \
            xqX[0] = *(const f32x4*)(p);                                    \
            xqX[1] = *(const f32x4*)(p + 4);                                \
            xqX[2] = *(const f32x4*)(p + 32);                               \
            xqX[3] = *(const f32x4*)(p + 36);                               \
        }                                                                   \
        f32x4 ar  = {br, br, br, br},     az  = {bz, bz, bz, bz};           \
        f32x4 ani = {bni, bni, bni, bni}, anh = {bnh, bnh, bnh, bnh};       \
        ar  = MFMA16(ax0, Bxr[0], ar);                                      \
        az  = MFMA16(ax0, Bxz[0], az);                                      \
        ani = MFMA16(ax0, Bxn[0], ani);                                     \
        ar  = MFMA16(ax1, Bxr[1], ar);                                      \
        az  = MFMA16(ax1, Bxz[1], az);                                      \
        ani = MFMA16(ax1, Bxn[1], ani);                                     \
        _Pragma("unroll")                                                   \
        for (int s = 0; s < 4; ++s) {                                       \
            half8 ah = *(const half8*)&s_h[P][aoff + s * 32];               \
            ar  = MFMA16(ah, Bhr[s], ar);                                   \
            az  = MFMA16(ah, Bhz[s], az);                                   \
            anh = MFMA16(ah, Bhn[s], anh);                                  \
        }                                                                   \
        float r = sigmoidf_(ar[0]);                                         \
        float z = sigmoidf_(az[0]);                                         \
        float n = tanhf_(ani[0] + r * anh[0]);                              \
        hp = n + z * (hp - n);                                              \
        s_h[P ^ 1][quad * HC + rr] = (half_t)hp;                            \
        BAR();                                                              \
    }

__global__ __launch_bounds__(512, 2)
void gru_rec0(const float* __restrict__ x, const float* __restrict__ Wih,
              const float* __restrict__ Whh, const float* __restrict__ bih,
              const float* __restrict__ bhh, half_t* __restrict__ h1)
{
    const int tid  = threadIdx.x;
    const int w    = tid >> 6;
    const int lane = tid & 63;
    const int quad = lane >> 4;
    const int col  = lane & 15;
    const int cb   = blockIdx.x * CPB;

    __shared__ alignas(16) half_t s_h[2][CPB * HC];

    const int rr = w * 16 + col;
    half8 Bxr[2], Bxz[2], Bxn[2];       // Wih (K=64)
    half8 Bhr[4], Bhz[4], Bhn[4];       // Whh (K=128)
#pragma unroll
    for (int s = 0; s < 2; ++s) {
        Bxr[s] = cvt8(Wih + (rr      ) * 64 + s * 32 + quad * 8);
        Bxz[s] = cvt8(Wih + (rr + 128) * 64 + s * 32 + quad * 8);
        Bxn[s] = cvt8(Wih + (rr + 256) * 64 + s * 32 + quad * 8);
    }
#pragma unroll
    for (int s = 0; s < 4; ++s) {
        Bhr[s] = cvt8(Whh + (rr      ) * 128 + s * 32 + quad * 8);
        Bhz[s] = cvt8(Whh + (rr + 128) * 128 + s * 32 + quad * 8);
        Bhn[s] = cvt8(Whh + (rr + 256) * 128 + s * 32 + quad * 8);
    }
    const float br  = bih[rr] + bhh[rr];
    const float bz  = bih[128 + rr] + bhh[128 + rr];
    const float bni = bih[256 + rr];
    const float bnh = bhh[256 + rr];

    for (int i = tid; i < CPB * HC; i += 512) s_h[0][i] = (half_t)0.0f;

    // A-fragment global source: chain = col>>2 (4-lane replicated)
    const float* xA = x + ((size_t)(cb + (col >> 2)) * SS) * 64 + quad * 8;
    f32x4 xq0[4], xq1[4];               // statically-indexed queues
    xq0[0] = *(const f32x4*)(xA);       xq0[1] = *(const f32x4*)(xA + 4);
    xq0[2] = *(const f32x4*)(xA + 32);  xq0[3] = *(const f32x4*)(xA + 36);
    xq1[0] = *(const f32x4*)(xA + 64);  xq1[1] = *(const f32x4*)(xA + 68);
    xq1[2] = *(const f32x4*)(xA + 96);  xq1[3] = *(const f32x4*)(xA + 100);

    // h1 copy-out mapping (256 threads, 4B each)
    const int c  = (tid >> 6) & 3;
    const int sc = tid & 63;
    uint32_t* h1u = (uint32_t*)(h1 + (size_t)(cb + c) * SS * 128) + sc;

    __syncthreads();

    float hp = 0.0f;
    const int aoff = (col >> 2) * HC + quad * 8;

    for (int t = 0; t < SS; t += 2) {
        R0_STEP(0, xq0, t);
        R0_STEP(1, xq1, t + 1);
    }
    if (tid < 256) {    // final h[1023] sits in s_h[0]
        uint32_t v = *(const uint32_t*)&s_h[0][c * HC + 2 * sc];
        h1u[(size_t)(SS - 1) * 64] = v;
    }
}

// ------------- Layer 1: h1[B,S,128] f16 -> FC -> out[B,10] f32 -------------
#define R1_STEP(P, hqX, t)                                                  \
    {                                                                       \
        f32x4 ar  = {br, br, br, br},     az  = {bz, bz, bz, bz};           \
        f32x4 ani = {bni, bni, bni, bni}, anh = {bnh, bnh, bnh, bnh};       \
        _Pragma("unroll")                                                   \
        for (int s = 0; s < 4; ++s) {                                       \
            half8 ah = *(const half8*)&s_h[P][aoff + s * 32];               \
            ar  = MFMA16(hqX[s], Bxr[s], ar);                               \
            ar  = MFMA16(ah, Bhr[s], ar);                                   \
            az  = MFMA16(hqX[s], Bxz[s], az);                               \
            az  = MFMA16(ah, Bhz[s], az);                                   \
            ani = MFMA16(hqX[s], Bxn[s], ani);                              \
            anh = MFMA16(ah, Bhn[s], anh);                                  \
        }                                                                   \
        if ((t) + 2 < SS) {                                                 \
            const half_t* p = xA + (size_t)((t) + 2) * 128;                 \
            _Pragma("unroll")                                               \
            for (int s = 0; s < 4; ++s)                                     \
                hqX[s] = *(const half8*)(p + s * 32);                       \
        }                                                                   \
        float r = sigmoidf_(ar[0]);                                         \
        float z = sigmoidf_(az[0]);                                         \
        float n = tanhf_(ani[0] + r * anh[0]);                              \
        hp = n + z * (hp - n);                                              \
        s_h[P ^ 1][quad * HC + rr] = (half_t)hp;                            \
        BAR();                                                              \
    }

__global__ __launch_bounds__(512, 2)
void gru_rec1(const half_t* __restrict__ h1, const float* __restrict__ Wih,
              const float* __restrict__ Whh, const float* __restrict__ bih,
              const float* __restrict__ bhh, const float* __restrict__ fcw,
              const float* __restrict__ fcb, float* __restrict__ out)
{
    const int tid  = threadIdx.x;
    const int w    = tid >> 6;
    const int lane = tid & 63;
    const int quad = lane >> 4;
    const int col  = lane & 15;
    const int cb   = blockIdx.x * CPB;

    __shared__ alignas(16) half_t s_h[2][CPB * HC];

    const int rr = w * 16 + col;
    half8 Bxr[4], Bxz[4], Bxn[4];       // Wih (K=128)
    half8 Bhr[4], Bhz[4], Bhn[4];       // Whh (K=128)
#pragma unroll
    for (int s = 0; s < 4; ++s) {
        Bxr[s] = cvt8(Wih + (rr      ) * 128 + s * 32 + quad * 8);
        Bxz[s] = cvt8(Wih + (rr + 128) * 128 + s * 32 + quad * 8);
        Bxn[s] = cvt8(Wih + (rr + 256) * 128 + s * 32 + quad * 8);
        Bhr[s] = cvt8(Whh + (rr      ) * 128 + s * 32 + quad * 8);
        Bhz[s] = cvt8(Whh + (rr + 128) * 128 + s * 32 + quad * 8);
        Bhn[s] = cvt8(Whh + (rr + 256) * 128 + s * 32 + quad * 8);
    }
    const float br  = bih[rr] + bhh[rr];
    const float bz  = bih[128 + rr] + bhh[128 + rr];
    const float bni = bih[256 + rr];
    const float bnh = bhh[256 + rr];

    for (int i = tid; i < CPB * HC; i += 512) s_h[0][i] = (half_t)0.0f;

    // x (= h0 stream) A-fragments straight from global, two static queues
    const half_t* xA = h1 + ((size_t)(cb + (col >> 2)) * SS) * 128 + quad * 8;
    half8 hq0[4], hq1[4];
#pragma unroll
    for (int s = 0; s < 4; ++s) {
        hq0[s] = *(const half8*)(xA + s * 32);
        hq1[s] = *(const half8*)(xA + 128 + s * 32);
    }

    __syncthreads();

    float hp = 0.0f;
    const int aoff = (col >> 2) * HC + quad * 8;

    for (int t = 0; t < SS; t += 2) {
        R1_STEP(0, hq0, t);
        R1_STEP(1, hq1, t + 1);
    }
    __syncthreads();

    // FC epilogue: h_final (t=1023 wrote buffer 0) rows 0..3
    if (tid < 40) {
        const int ch = tid / 10, cl = tid - ch * 10;
        float acc = fcb[cl];
        const float* wr = fcw + cl * 128;
        const half_t* hv = &s_h[0][ch * HC];
#pragma unroll 8
        for (int k = 0; k < 128; ++k) acc += (float)hv[k] * wr[k];
        out[(cb + ch) * 10 + cl] = acc;
    }
}

extern "C" void kernel_launch(void* const* d_in, const int* in_sizes, int n_in,
                              void* d_out, int out_size, void* d_ws, size_t ws_size,
                              hipStream_t stream) {
    const float* x    = (const float*)d_in[0];
    const float* Wih0 = (const float*)d_in[1];
    const float* Whh0 = (const float*)d_in[2];
    const float* bih0 = (const float*)d_in[3];
    const float* bhh0 = (const float*)d_in[4];
    const float* Wih1 = (const float*)d_in[5];
    const float* Whh1 = (const float*)d_in[6];
    const float* bih1 = (const float*)d_in[7];
    const float* bhh1 = (const float*)d_in[8];
    const float* fcw  = (const float*)d_in[9];
    const float* fcb  = (const float*)d_in[10];

    half_t* h1 = (half_t*)d_ws;   // [512,1024,128] f16 = 134 MB

    gru_rec0<<<NBLK, 512, 0, stream>>>(x, Wih0, Whh0, bih0, bhh0, h1);
    gru_rec1<<<NBLK, 512, 0, stream>>>(h1, Wih1, Whh1, bih1, bhh1, fcw, fcb,
                                       (float*)d_out);
}

// Round 9
// 1170.660 us; speedup vs baseline: 58.6048x; 1.1282x over previous
//
#include <hip/hip_runtime.h>
#include <stdint.h>

// TinyGRU R9: FUSED layers, CPB=4, 128 blocks, 512 thr (2 waves/SIMD).
// R8 post-mortem: rec1 step = ~55% MFMA issue + ~45% serial latency (barrier,
// ds round-trip, gate transcendentals); LDS tweaks changed nothing. Fusing
// both layers (layer1 lags one step) fills each layer's latency shadow with
// the other's MFMAs and halves serial steps 2048 -> 1025. Register budget at
// CPB=4: 42 B-frag half8 (168) + acc 32 + misc ~40 = ~240 < 256 (R3's CPB=16
// fusion died at ~270). Only REGISTER arrays need static indexing (R7/R8
// lesson) -> LDS parity stays dynamic, single clean loop.
// Layer1 x-fragment == layer0 h-fragment (one ds_read feeds 6 MFMAs).
// No h1 global round-trip at all. x staged via R4-proven LDS 4-step chunks.
// HC=144 / XC=72 so every ds_read_b128 is 16B-aligned.

typedef _Float16 half_t;
typedef _Float16 half8 __attribute__((ext_vector_type(8)));
typedef __fp16  fp16x2 __attribute__((ext_vector_type(2)));
typedef float f32x4 __attribute__((ext_vector_type(4)));

#define SS 1024
#define CPB 4
#define NBLK 128
#define CT 4              // x chunk depth (steps)
#define HC 144            // h row stride (f16): 288B, 16B-aligned
#define XC 72             // x row stride (f16): 144B, 16B-aligned

#define MFMA16(a, b, c) __builtin_amdgcn_mfma_f32_16x16x32_f16(a, b, c, 0, 0, 0)

// lgkmcnt(0), vmcnt=63 (no wait), expcnt=7 (no wait)  [gfx9 encoding]
#define BAR() do { __builtin_amdgcn_sched_barrier(0);                 \
                   __builtin_amdgcn_s_waitcnt(0xC07F);                \
                   __builtin_amdgcn_s_barrier();                      \
                   __builtin_amdgcn_sched_barrier(0); } while (0)

__device__ __forceinline__ float sigmoidf_(float x) {
    return __builtin_amdgcn_rcpf(1.0f + __expf(-x));
}
__device__ __forceinline__ float tanhf_(float x) {
    return 1.0f - 2.0f * __builtin_amdgcn_rcpf(1.0f + __expf(2.0f * x));
}
union H8 { half8 v; fp16x2 p[4]; };
__device__ __forceinline__ half8 pack8(f32x4 a, f32x4 b) {
    H8 u;
    u.p[0] = __builtin_amdgcn_cvt_pkrtz(a[0], a[1]);
    u.p[1] = __builtin_amdgcn_cvt_pkrtz(a[2], a[3]);
    u.p[2] = __builtin_amdgcn_cvt_pkrtz(b[0], b[1]);
    u.p[3] = __builtin_amdgcn_cvt_pkrtz(b[2], b[3]);
    return u.v;
}
__device__ __forceinline__ half8 cvt8(const float* p) {
    return pack8(*(const f32x4*)p, *(const f32x4*)(p + 4));
}

// One fused timestep. DO_L0/DO_L1 are literal 0/1 (dead code folds).
// Layer0 computes h0[u]; layer1 computes h1[u-1] (x-input = h0[u-1]).
#define STEP(u, DO_L0, DO_L1)                                               \
  {                                                                         \
    const int cur = (u) & 1, nxt = cur ^ 1;                                 \
    f32x4 ar0  = {b0r, b0r, b0r, b0r},     az0  = {b0z, b0z, b0z, b0z};     \
    f32x4 ani0 = {b0ni, b0ni, b0ni, b0ni}, anh0 = {b0nh, b0nh, b0nh, b0nh}; \
    f32x4 ar1  = {b1r, b1r, b1r, b1r},     az1  = {b1z, b1z, b1z, b1z};     \
    f32x4 ani1 = {b1ni, b1ni, b1ni, b1ni}, anh1 = {b1nh, b1nh, b1nh, b1nh}; \
    if (DO_L0) {                                                            \
      const half_t* xb = &s_x[((u) >> 2) & 1][(u) & 3][axoff];              \
      half8 ax0 = *(const half8*)(xb);                                      \
      half8 ax1 = *(const half8*)(xb + 32);                                 \
      ar0  = MFMA16(ax0, B0xr[0], ar0);  ar0  = MFMA16(ax1, B0xr[1], ar0);  \
      az0  = MFMA16(ax0, B0xz[0], az0);  az0  = MFMA16(ax1, B0xz[1], az0);  \
      ani0 = MFMA16(ax0, B0xn[0], ani0); ani0 = MFMA16(ax1, B0xn[1], ani0); \
    }                                                                       \
    _Pragma("unroll")                                                       \
    for (int s = 0; s < 4; ++s) {                                           \
      half8 ah0 = *(const half8*)&s_h0[cur][aoff + s * 32];                 \
      if (DO_L0) {                                                          \
        ar0  = MFMA16(ah0, B0hr[s], ar0);                                   \
        az0  = MFMA16(ah0, B0hz[s], az0);                                   \
        anh0 = MFMA16(ah0, B0hn[s], anh0);                                  \
      }                                                                     \
      if (DO_L1) {                                                          \
        half8 ah1 = *(const half8*)&s_h1[cur][aoff + s * 32];               \
        ar1  = MFMA16(ah0, B1xr[s], ar1);                                   \
        az1  = MFMA16(ah0, B1xz[s], az1);                                   \
        ani1 = MFMA16(ah0, B1xn[s], ani1);                                  \
        ar1  = MFMA16(ah1, B1hr[s], ar1);                                   \
        az1  = MFMA16(ah1, B1hz[s], az1);                                   \
        anh1 = MFMA16(ah1, B1hn[s], anh1);                                  \
      }                                                                     \
    }                                                                       \
    if (DO_L0) {                                                            \
      float r = sigmoidf_(ar0[0]);                                          \
      float z = sigmoidf_(az0[0]);                                          \
      float n = tanhf_(ani0[0] + r * anh0[0]);                              \
      hp0 = n + z * (hp0 - n);                                              \
      s_h0[nxt][quad * HC + rr] = (half_t)hp0;                              \
    }                                                                       \
    if (DO_L1) {                                                            \
      float r = sigmoidf_(ar1[0]);                                          \
      float z = sigmoidf_(az1[0]);                                          \
      float n = tanhf_(ani1[0] + r * anh1[0]);                              \
      hp1 = n + z * (hp1 - n);                                              \
      s_h1[nxt][quad * HC + rr] = (half_t)hp1;                              \
    }                                                                       \
    if (DO_L0 && ((u) & 3) == 3 && (u) + 1 < SS && tid < 256) {             \
      const int c1 = ((u) + 1) >> 2;                                        \
      _Pragma("unroll")                                                     \
      for (int i = 0; i < CT; ++i)                                          \
        s_x[c1 & 1][i][c * XC + sc] = (half_t)gq[i];                        \
      const int base = (c1 + 1) * CT;                                       \
      if (base < SS) {                                                      \
        _Pragma("unroll")                                                   \
        for (int i = 0; i < CT; ++i)                                        \
          gq[i] = xrow[(size_t)(base + i) * 64];                            \
      }                                                                     \
    }                                                                       \
    BAR();                                                                  \
  }

__global__ __launch_bounds__(512, 2)
void gru_fused(const float* __restrict__ x,
               const float* __restrict__ Wih0, const float* __restrict__ Whh0,
               const float* __restrict__ bih0, const float* __restrict__ bhh0,
               const float* __restrict__ Wih1, const float* __restrict__ Whh1,
               const float* __restrict__ bih1, const float* __restrict__ bhh1,
               const float* __restrict__ fcw, const float* __restrict__ fcb,
               float* __restrict__ out)
{
    const int tid  = threadIdx.x;
    const int w    = tid >> 6;
    const int lane = tid & 63;
    const int quad = lane >> 4;
    const int col  = lane & 15;
    const int cb   = blockIdx.x * CPB;

    __shared__ alignas(16) half_t s_x[2][CT][CPB * XC];
    __shared__ alignas(16) half_t s_h0[2][CPB * HC];
    __shared__ alignas(16) half_t s_h1[2][CPB * HC];

    const int rr = w * 16 + col;
    // ---- weights into register B-fragments (reused ~1024x) ----
    half8 B0xr[2], B0xz[2], B0xn[2], B0hr[4], B0hz[4], B0hn[4];
    half8 B1xr[4], B1xz[4], B1xn[4], B1hr[4], B1hz[4], B1hn[4];
#pragma unroll
    for (int s = 0; s < 2; ++s) {
        B0xr[s] = cvt8(Wih0 + (rr      ) * 64 + s * 32 + quad * 8);
        B0xz[s] = cvt8(Wih0 + (rr + 128) * 64 + s * 32 + quad * 8);
        B0xn[s] = cvt8(Wih0 + (rr + 256) * 64 + s * 32 + quad * 8);
    }
#pragma unroll
    for (int s = 0; s < 4; ++s) {
        B0hr[s] = cvt8(Whh0 + (rr      ) * 128 + s * 32 + quad * 8);
        B0hz[s] = cvt8(Whh0 + (rr + 128) * 128 + s * 32 + quad * 8);
        B0hn[s] = cvt8(Whh0 + (rr + 256) * 128 + s * 32 + quad * 8);
        B1xr[s] = cvt8(Wih1 + (rr      ) * 128 + s * 32 + quad * 8);
        B1xz[s] = cvt8(Wih1 + (rr + 128) * 128 + s * 32 + quad * 8);
        B1xn[s] = cvt8(Wih1 + (rr + 256) * 128 + s * 32 + quad * 8);
        B1hr[s] = cvt8(Whh1 + (rr      ) * 128 + s * 32 + quad * 8);
        B1hz[s] = cvt8(Whh1 + (rr + 128) * 128 + s * 32 + quad * 8);
        B1hn[s] = cvt8(Whh1 + (rr + 256) * 128 + s * 32 + quad * 8);
    }
    const float b0r  = bih0[rr] + bhh0[rr];
    const float b0z  = bih0[128 + rr] + bhh0[128 + rr];
    const float b0ni = bih0[256 + rr];
    const float b0nh = bhh0[256 + rr];
    const float b1r  = bih1[rr] + bhh1[rr];
    const float b1z  = bih1[128 + rr] + bhh1[128 + rr];
    const float b1ni = bih1[256 + rr];
    const float b1nh = bhh1[256 + rr];

    // zero h state: s_h0[0] (h0[-1]), s_h1[0] & s_h1[1] (h1[-2], h1[-1])
    for (int i = tid; i < CPB * HC; i += 512) {
        s_h0[0][i] = (half_t)0.0f;
        s_h1[0][i] = (half_t)0.0f;
        s_h1[1][i] = (half_t)0.0f;
    }

    // ---- x staging (R4-proven): tid<256 -> (chain c, col sc) ----
    const int c  = (tid >> 6) & 3;
    const int sc = tid & 63;
    const float* xrow = x + (size_t)(cb + c) * SS * 64 + sc;
    float gq[CT];
    if (tid < 256) {
#pragma unroll
        for (int i = 0; i < CT; ++i) gq[i] = xrow[i * 64];
#pragma unroll
        for (int i = 0; i < CT; ++i)            // publish chunk 0
            s_x[0][i][c * XC + sc] = (half_t)gq[i];
#pragma unroll
        for (int i = 0; i < CT; ++i)            // issue chunk 1
            gq[i] = xrow[(CT + i) * 64];
    }
    __syncthreads();

    float hp0 = 0.0f, hp1 = 0.0f;
    const int aoff  = (col >> 2) * HC + quad * 8;
    const int axoff = (col >> 2) * XC + quad * 8;

    STEP(0, 1, 0);                         // u=0: layer0 only (h0[0])
    for (int u = 1; u < SS; ++u) {         // u=1..1023: both layers
        STEP(u, 1, 1);
    }
    STEP(SS, 0, 1);                        // u=1024: layer1 only (h1[1023])

    // ---- FC epilogue: h1_final in s_h1[1] (u=1024: nxt=1) ----
    if (tid < 40) {
        const int ch = tid / 10, cl = tid - ch * 10;
        float acc = fcb[cl];
        const float* wr = fcw + cl * 128;
        const half_t* hv = &s_h1[1][ch * HC];
#pragma unroll 8
        for (int k = 0; k < 128; ++k) acc += (float)hv[k] * wr[k];
        out[(cb + ch) * 10 + cl] = acc;
    }
}

extern "C" void kernel_launch(void* const* d_in, const int* in_sizes, int n_in,
                              void* d_out, int out_size, void* d_ws, size_t ws_size,
                              hipStream_t stream) {
    const float* x    = (const float*)d_in[0];
    const float* Wih0 = (const float*)d_in[1];
    const float* Whh0 = (const float*)d_in[2];
    const float* bih0 = (const float*)d_in[3];
    const float* bhh0 = (const float*)d_in[4];
    const float* Wih1 = (const float*)d_in[5];
    const float* Whh1 = (const float*)d_in[6];
    const float* bih1 = (const float*)d_in[7];
    const float* bhh1 = (const float*)d_in[8];
    const float* fcw  = (const float*)d_in[9];
    const float* fcb  = (const float*)d_in[10];

    gru_fused<<<NBLK, 512, 0, stream>>>(x, Wih0, Whh0, bih0, bhh0,
                                        Wih1, Whh1, bih1, bhh1,
                                        fcw, fcb, (float*)d_out);
}